// Round 4
// baseline (747.290 us; speedup 1.0000x reference)
//
#include <hip/hip_runtime.h>
#include <stdint.h>

// Problem: B=8, SQ=SK=4096, D=128, fp32 in/out.
// out = softmax(QK^T/inv_scale) * jax-threefry-dropout-mask / (1-pm) @ V
// RNG: JAX *partitionable* threefry (default since jax 0.5):
//   bits[n] = o0 ^ o1 where (o0,o1) = threefry2x32(key=(0,42), x=(0, n))
#define Bn  8
#define SQn 4096
#define SKn 4096
#define Dn  128
#define QTn 64
#define KTn 64
static constexpr uint32_t NTOT = 134217728u;  // 8*4096*4096

typedef __attribute__((ext_vector_type(8))) short short8;   // 8 bf16 (4 VGPRs) MFMA A/B frag
typedef __attribute__((ext_vector_type(4))) short short4v;
typedef __attribute__((ext_vector_type(4))) float f32x4;    // MFMA C/D frag

__device__ __forceinline__ short f2bf(float f) {
  // RNE float->bf16 (no NaN inputs in this problem)
  uint32_t x = __float_as_uint(f);
  uint32_t r = (x + 0x7FFFu + ((x >> 16) & 1u)) >> 16;
  return (short)r;
}

__device__ __forceinline__ uint32_t rotl32(uint32_t x, uint32_t r) {
  return (x << r) | (x >> (32u - r));
}

// JAX threefry2x32, key = (0, 42)  [jax.random.key(42)]
__device__ __forceinline__ void tf2x32(uint32_t x0, uint32_t x1, uint32_t& o0, uint32_t& o1) {
  const uint32_t k0 = 0u, k1 = 42u, k2 = 0x1BD11BF0u;  // 0 ^ 42 ^ 0x1BD11BDA
  x0 += k0; x1 += k1;
#define TFR(r) { x0 += x1; x1 = rotl32(x1, r); x1 ^= x0; }
  TFR(13) TFR(15) TFR(26) TFR(6)  x0 += k1; x1 += k2 + 1u;
  TFR(17) TFR(29) TFR(16) TFR(24) x0 += k2; x1 += k0 + 2u;
  TFR(13) TFR(15) TFR(26) TFR(6)  x0 += k0; x1 += k1 + 3u;
  TFR(17) TFR(29) TFR(16) TFR(24) x0 += k1; x1 += k2 + 4u;
  TFR(13) TFR(15) TFR(26) TFR(6)  x0 += k2; x1 += k0 + 5u;
#undef TFR
  o0 = x0; o1 = x1;
}

__device__ __forceinline__ bool keep_from_bits(uint32_t bits, float pkeep) {
  // jax.random.uniform: ((bits>>9)|0x3F800000) as float - 1.0, then  u < pkeep
  float u = __uint_as_float((bits >> 9) | 0x3F800000u) - 1.0f;
  return u < pkeep;
}

// Precompute dropout keep-mask bits into ws (partitionable threefry: one eval
// per element, counter = (0, n), bits = o0^o1). Thread T covers flat
// idx [T*32, T*32+32).
__global__ __launch_bounds__(256) void mask_gen(const float* __restrict__ p_pd,
                                                uint32_t* __restrict__ mask) {
  uint32_t T = blockIdx.x * 256u + threadIdx.x;
  float pkeep = 1.0f - p_pd[0];
  uint32_t base = T * 32u;
  uint32_t w0 = 0u;
#pragma unroll 8
  for (uint32_t j = 0; j < 32u; j++) {
    uint32_t o0, o1;
    tf2x32(0u, base + j, o0, o1);
    w0 |= (keep_from_bits(o0 ^ o1, pkeep) ? 1u : 0u) << j;
  }
  mask[T] = w0;
}

// Flash attention. 256 threads = 4 waves; wave w owns q-band [w*16, w*16+16).
// mfma_f32_16x16x32_bf16 layouts (guide §3, m89/m91-verified):
//   A: row=l&15, k=(l>>4)*8+i (8 contiguous);  B: col=l&15, same k
//   C/D: col=l&15, row=(l>>4)*4+reg
template <int USE_MASK>
__global__ __launch_bounds__(256, 2) void attn(
    const float* __restrict__ Qg, const float* __restrict__ Kg, const float* __restrict__ Vg,
    const float* __restrict__ p_inv, const float* __restrict__ p_pd, const float* __restrict__ p_pm,
    const uint2* __restrict__ maskw2, float* __restrict__ Out) {
  // K tile [key][d] bf16, 256B rows, XOR-swizzle (row&7)<<3 shorts -> 2-way reads
  __shared__ __align__(16) short Kt[KTn * Dn];
  // V tile transposed [d][key] bf16, 128B rows, XOR ((d>>2)&7)<<3 -> ~4-way
  __shared__ __align__(16) short Vt[Dn * KTn];
  // P tile [q][key] bf16, padded to 72 shorts/row (144B) -> 2-way reads
  __shared__ __align__(16) short Pt[QTn * 72];

  const int tid = threadIdx.x;
  const int w = tid >> 6;          // wave 0..3
  const int lane = tid & 63;
  const int m = lane & 15;         // MFMA "col" lane index
  const int h = lane >> 4;         // MFMA k-group / row-group
  const int gid = blockIdx.x;
  const int b = gid & 7;           // batch -> XCD pinned
  const int q0 = (gid >> 3) * QTn;

  const float rscale = 1.0f / p_inv[0];
  const float pd = p_pd[0], pm = p_pm[0];
  const float pkeep = 1.0f - pd;
  const float oscale_c = 1.0f / ((1.0f - pd) * (1.0f - pm));

  // ---- preload Q fragments (band row = l&15), bf16 ----
  short8 qf[4];
  {
    const float* qp = Qg + ((size_t)(b * SQn + q0 + w * 16 + m)) * Dn;
#pragma unroll
    for (int c = 0; c < 4; c++) {
      float4 a = *reinterpret_cast<const float4*>(qp + c * 32 + h * 8);
      float4 a2 = *reinterpret_cast<const float4*>(qp + c * 32 + h * 8 + 4);
      short8 v;
      v[0] = f2bf(a.x);  v[1] = f2bf(a.y);  v[2] = f2bf(a.z);  v[3] = f2bf(a.w);
      v[4] = f2bf(a2.x); v[5] = f2bf(a2.y); v[6] = f2bf(a2.z); v[7] = f2bf(a2.w);
      qf[c] = v;
    }
  }

  f32x4 acc[8];
#pragma unroll
  for (int dt = 0; dt < 8; dt++) acc[dt] = (f32x4){0.f, 0.f, 0.f, 0.f};
  float m_run[4], l_run[4];
  uint32_t rowb[4];  // flat-bit row bases for inline threefry path
#pragma unroll
  for (int r = 0; r < 4; r++) {
    m_run[r] = -1e30f;
    l_run[r] = 0.f;
    rowb[r] = (uint32_t)(b * SQn + q0 + w * 16 + 4 * h + r) * (uint32_t)SKn;
  }

  const size_t kvbase = (size_t)b * SKn * Dn;

  for (int kt = 0; kt < SKn / KTn; kt++) {
    __syncthreads();  // everyone done reading Kt/Vt of previous tile
    // ---- stage K tile ----
    {
      const float* kp = Kg + kvbase + (size_t)kt * KTn * Dn;
#pragma unroll
      for (int p = 0; p < 8; p++) {
        int idx = p * 256 + tid;
        int row = idx >> 5, dq = idx & 31;
        float4 x = *reinterpret_cast<const float4*>(kp + row * Dn + dq * 4);
        short4v sv;
        sv[0] = f2bf(x.x); sv[1] = f2bf(x.y); sv[2] = f2bf(x.z); sv[3] = f2bf(x.w);
        *reinterpret_cast<short4v*>(&Kt[row * 128 + ((dq * 4) ^ ((row & 7) << 3))]) = sv;
      }
    }
    // ---- stage V tile (transposed, key-pairs -> b32 writes) ----
    {
      const float* vp = Vg + kvbase + (size_t)kt * KTn * Dn;
#pragma unroll
      for (int p = 0; p < 4; p++) {
        int idx = p * 256 + tid;
        int kp2 = idx >> 5, dq = idx & 31;
        float4 v0 = *reinterpret_cast<const float4*>(vp + (2 * kp2) * Dn + dq * 4);
        float4 v1 = *reinterpret_cast<const float4*>(vp + (2 * kp2 + 1) * Dn + dq * 4);
        int swz = (dq & 7) << 3;  // == ((d>>2)&7)<<3 for d=dq*4+i
        const float* f0 = &v0.x;
        const float* f1 = &v1.x;
#pragma unroll
        for (int i = 0; i < 4; i++) {
          int d = dq * 4 + i;
          uint32_t pk = ((uint32_t)(uint16_t)f2bf(f0[i])) |
                        (((uint32_t)(uint16_t)f2bf(f1[i])) << 16);
          *reinterpret_cast<uint32_t*>(&Vt[d * 64 + ((2 * kp2) ^ swz)]) = pk;
        }
      }
    }
    __syncthreads();  // tiles visible

    // ---- mask prefetch (4 u64 per lane, L2-hit) ----
    uint2 mw[4];
    if (USE_MASK) {
#pragma unroll
      for (int r = 0; r < 4; r++) {
        uint32_t widx = (uint32_t)(b * SQn + q0 + w * 16 + 4 * h + r) * 64u + (uint32_t)kt;
        mw[r] = maskw2[widx];
      }
    }

    // ---- QK^T: S[4h+r][t*16+m] ----
    f32x4 sfr[4];
#pragma unroll
    for (int t = 0; t < 4; t++) {
      f32x4 s = (f32x4){0.f, 0.f, 0.f, 0.f};
      int krow = t * 16 + m;
      int swzk = (krow & 7) << 3;
#pragma unroll
      for (int c = 0; c < 4; c++) {
        short8 kf = *reinterpret_cast<const short8*>(&Kt[krow * 128 + ((c * 32 + h * 8) ^ swzk)]);
        s = __builtin_amdgcn_mfma_f32_16x16x32_bf16(qf[c], kf, s, 0, 0, 0);
      }
      sfr[t] = s;
    }

    // ---- online softmax (all in registers; reduce over 16 col-lanes) ----
    float oscl[4];
    float pv[4][4];  // [t][r]
#pragma unroll
    for (int r = 0; r < 4; r++) {
      float s0 = sfr[0][r] * rscale, s1 = sfr[1][r] * rscale;
      float s2 = sfr[2][r] * rscale, s3 = sfr[3][r] * rscale;
      float tmax = fmaxf(fmaxf(s0, s1), fmaxf(s2, s3));
#pragma unroll
      for (int off = 1; off < 16; off <<= 1) tmax = fmaxf(tmax, __shfl_xor(tmax, off, 64));
      float mnew = fmaxf(m_run[r], tmax);
      float al = __expf(m_run[r] - mnew);
      float e0 = __expf(s0 - mnew), e1 = __expf(s1 - mnew);
      float e2 = __expf(s2 - mnew), e3 = __expf(s3 - mnew);
      float ts = e0 + e1 + e2 + e3;
#pragma unroll
      for (int off = 1; off < 16; off <<= 1) ts += __shfl_xor(ts, off, 64);
      l_run[r] = l_run[r] * al + ts;   // denominator is PRE-dropout sum
      m_run[r] = mnew;
      oscl[r] = al;
      pv[0][r] = e0; pv[1][r] = e1; pv[2][r] = e2; pv[3][r] = e3;
    }
#pragma unroll
    for (int dt = 0; dt < 8; dt++) {
#pragma unroll
      for (int r = 0; r < 4; r++) acc[dt][r] *= oscl[r];
    }

    // ---- dropout + write P (wave-private LDS re-layout C-frag -> A-frag) ----
#pragma unroll
    for (int r = 0; r < 4; r++) {
      int qrow = w * 16 + 4 * h + r;
#pragma unroll
      for (int t = 0; t < 4; t++) {
        bool kp;
        if (USE_MASK) {
          uint32_t wm = (t < 2) ? mw[r].x : mw[r].y;
          kp = (wm >> ((t & 1) * 16 + m)) & 1u;
        } else {
          uint32_t n = rowb[r] + (uint32_t)(kt * 64 + t * 16 + m);
          uint32_t o0, o1;
          tf2x32(0u, n, o0, o1);
          kp = keep_from_bits(o0 ^ o1, pkeep);
        }
        float pmv = kp ? pv[t][r] : 0.0f;
        Pt[qrow * 72 + t * 16 + m] = f2bf(pmv);
      }
    }

    // ---- PV: acc += P @ V  (no barrier: Pt rows are wave-private) ----
#pragma unroll
    for (int c = 0; c < 2; c++) {
      short8 pa = *reinterpret_cast<const short8*>(&Pt[(w * 16 + m) * 72 + c * 32 + h * 8]);
#pragma unroll
      for (int dt = 0; dt < 8; dt++) {
        int d = dt * 16 + m;
        short8 vb = *reinterpret_cast<const short8*>(
            &Vt[d * 64 + ((c * 32 + h * 8) ^ (((d >> 2) & 7) << 3))]);
        acc[dt] = __builtin_amdgcn_mfma_f32_16x16x32_bf16(pa, vb, acc[dt], 0, 0, 0);
      }
    }
  }

  // ---- epilogue ----
#pragma unroll
  for (int r = 0; r < 4; r++) {
    float os = oscale_c / l_run[r];
    float* op = Out + (size_t)(b * SQn + q0 + w * 16 + 4 * h + r) * Dn;
#pragma unroll
    for (int dt = 0; dt < 8; dt++) op[dt * 16 + m] = acc[dt][r] * os;
  }
}

extern "C" void kernel_launch(void* const* d_in, const int* in_sizes, int n_in,
                              void* d_out, int out_size, void* d_ws, size_t ws_size,
                              hipStream_t stream) {
  const float* Qg = (const float*)d_in[0];
  const float* Kg = (const float*)d_in[1];
  const float* Vg = (const float*)d_in[2];
  const float* p_inv = (const float*)d_in[3];
  const float* p_pd = (const float*)d_in[4];
  const float* p_pm = (const float*)d_in[5];
  float* Out = (float*)d_out;

  const bool use_mask = ws_size >= (size_t)(NTOT / 8u);  // 16.8 MB of mask bits
  if (use_mask) {
    mask_gen<<<dim3(NTOT / 32u / 256u), dim3(256), 0, stream>>>(p_pd, (uint32_t*)d_ws);
    attn<1><<<dim3(512), dim3(256), 0, stream>>>(Qg, Kg, Vg, p_inv, p_pd, p_pm,
                                                 (const uint2*)d_ws, Out);
  } else {
    attn<0><<<dim3(512), dim3(256), 0, stream>>>(Qg, Kg, Vg, p_inv, p_pd, p_pm,
                                                 nullptr, Out);
  }
}

// Round 6
// 558.395 us; speedup vs baseline: 1.3383x; 1.3383x over previous
//
#include <hip/hip_runtime.h>
#include <stdint.h>

// Problem: B=8, SQ=SK=4096, D=128, fp32 in/out.
// out = softmax(QK^T/inv_scale) * jax-threefry-dropout-mask / (1-pm) @ V
// RNG: JAX partitionable threefry: bits[n] = o0^o1, (o0,o1)=tf2x32(key=(0,42),(0,n))
#define Bn  8
#define SQn 4096
#define SKn 4096
#define Dn  128
#define QTn 64
#define KTn 64
static constexpr uint32_t NTOT = 134217728u;  // 8*4096*4096

typedef __attribute__((ext_vector_type(8))) short short8;
typedef __attribute__((ext_vector_type(4))) short short4v;
typedef __attribute__((ext_vector_type(4))) float f32x4;

__device__ __forceinline__ short f2bf(float f) {
  uint32_t x = __float_as_uint(f);
  uint32_t r = (x + 0x7FFFu + ((x >> 16) & 1u)) >> 16;
  return (short)r;
}

__device__ __forceinline__ uint32_t rotl32(uint32_t x, uint32_t r) {
  return (x << r) | (x >> (32u - r));
}

// JAX threefry2x32, key = (0, 42)
__device__ __forceinline__ void tf2x32(uint32_t x0, uint32_t x1, uint32_t& o0, uint32_t& o1) {
  const uint32_t k0 = 0u, k1 = 42u, k2 = 0x1BD11BF0u;
  x0 += k0; x1 += k1;
#define TFR(r) { x0 += x1; x1 = rotl32(x1, r); x1 ^= x0; }
  TFR(13) TFR(15) TFR(26) TFR(6)  x0 += k1; x1 += k2 + 1u;
  TFR(17) TFR(29) TFR(16) TFR(24) x0 += k2; x1 += k0 + 2u;
  TFR(13) TFR(15) TFR(26) TFR(6)  x0 += k0; x1 += k1 + 3u;
  TFR(17) TFR(29) TFR(16) TFR(24) x0 += k1; x1 += k2 + 4u;
  TFR(13) TFR(15) TFR(26) TFR(6)  x0 += k2; x1 += k0 + 5u;
#undef TFR
  o0 = x0; o1 = x1;
}

__device__ __forceinline__ bool keep_from_bits(uint32_t bits, float pkeep) {
  float u = __uint_as_float((bits >> 9) | 0x3F800000u) - 1.0f;
  return u < pkeep;
}

// 16-lane (DPP row) rotation all-reduce: VALU-pipe, no LDS traffic.
template <int N>
__device__ __forceinline__ float ror16(float x) {
  int xi = __float_as_int(x);
  int r = __builtin_amdgcn_update_dpp(xi, xi, 0x120 | N, 0xF, 0xF, false);
  return __int_as_float(r);
}
__device__ __forceinline__ float redmax16(float x) {
  x = fmaxf(x, ror16<8>(x)); x = fmaxf(x, ror16<4>(x));
  x = fmaxf(x, ror16<2>(x)); x = fmaxf(x, ror16<1>(x));
  return x;
}
__device__ __forceinline__ float redsum16(float x) {
  x += ror16<8>(x); x += ror16<4>(x); x += ror16<2>(x); x += ror16<1>(x);
  return x;
}

// Precompute dropout keep-mask bits. Thread T covers flat idx [T*32, T*32+32).
__global__ __launch_bounds__(256) void mask_gen(const float* __restrict__ p_pd,
                                                uint32_t* __restrict__ mask) {
  uint32_t T = blockIdx.x * 256u + threadIdx.x;
  float pkeep = 1.0f - p_pd[0];
  uint32_t base = T * 32u;
  uint32_t w0 = 0u;
#pragma unroll 8
  for (uint32_t j = 0; j < 32u; j++) {
    uint32_t o0, o1;
    tf2x32(0u, base + j, o0, o1);
    w0 |= (keep_from_bits(o0 ^ o1, pkeep) ? 1u : 0u) << j;
  }
  mask[T] = w0;
}

// Flash attention. 256 threads = 4 waves; wave w owns q-band [w*16, w*16+16).
// TWO barriers per tile (round-4 discipline, replay-verified) + register
// prefetch of tile kt+1 issued before barrier-B so global latency hides
// under compute(kt). Single LDS buffer.
template <int USE_MASK>
__global__ __launch_bounds__(256, 2) void attn(
    const float* __restrict__ Qg, const float* __restrict__ Kg, const float* __restrict__ Vg,
    const float* __restrict__ p_inv, const float* __restrict__ p_pd, const float* __restrict__ p_pm,
    const uint2* __restrict__ maskw2, float* __restrict__ Out) {
  // K tile [key][d] bf16, XOR-swizzle (row&7)<<3 shorts -> 2-way reads
  __shared__ __align__(16) short Kt[KTn * Dn];
  // V tile transposed [d][key] bf16, XOR ((d>>2)&7)<<3 -> ~4-way
  __shared__ __align__(16) short Vt[Dn * KTn];
  // P tile [q][key] bf16, 72-short rows, inner ^ ((q&8)<<1) (wave-private rows)
  __shared__ __align__(16) short Pt[QTn * 72];

  const int tid = threadIdx.x;
  const int w = tid >> 6;
  const int lane = tid & 63;
  const int m = lane & 15;
  const int h = lane >> 4;
  const int gid = blockIdx.x;
  const int b = gid & 7;
  const int q0 = (gid >> 3) * QTn;

  const float rscale = 1.0f / p_inv[0];
  const float pd = p_pd[0], pm = p_pm[0];
  const float pkeep = 1.0f - pd;
  const float oscale_c = 1.0f / ((1.0f - pd) * (1.0f - pm));

  // ---- preload Q fragments with rscale folded in ----
  short8 qf[4];
  {
    const float* qp = Qg + ((size_t)(b * SQn + q0 + w * 16 + m)) * Dn;
#pragma unroll
    for (int c = 0; c < 4; c++) {
      float4 a = *reinterpret_cast<const float4*>(qp + c * 32 + h * 8);
      float4 a2 = *reinterpret_cast<const float4*>(qp + c * 32 + h * 8 + 4);
      short8 v;
      v[0] = f2bf(a.x * rscale);  v[1] = f2bf(a.y * rscale);
      v[2] = f2bf(a.z * rscale);  v[3] = f2bf(a.w * rscale);
      v[4] = f2bf(a2.x * rscale); v[5] = f2bf(a2.y * rscale);
      v[6] = f2bf(a2.z * rscale); v[7] = f2bf(a2.w * rscale);
      qf[c] = v;
    }
  }

  f32x4 acc[8];
#pragma unroll
  for (int dt = 0; dt < 8; dt++) acc[dt] = (f32x4){0.f, 0.f, 0.f, 0.f};
  float m_run[4], l_run[4];
  uint32_t rowb[4];
#pragma unroll
  for (int r = 0; r < 4; r++) {
    m_run[r] = -1e30f;
    l_run[r] = 0.f;
    rowb[r] = (uint32_t)(b * SQn + q0 + w * 16 + 4 * h + r) * (uint32_t)SKn;
  }

  const size_t kvbase = (size_t)b * SKn * Dn;

  float4 kreg[8], vreg[8];
  auto issue_loads = [&](int kt) {
    const float* kp = Kg + kvbase + (size_t)kt * KTn * Dn;
    const float* vp = Vg + kvbase + (size_t)kt * KTn * Dn;
#pragma unroll
    for (int p = 0; p < 8; p++) {
      int idx = p * 256 + tid;
      kreg[p] = *reinterpret_cast<const float4*>(kp + (idx >> 5) * Dn + (idx & 31) * 4);
    }
#pragma unroll
    for (int p = 0; p < 4; p++) {
      int idx = p * 256 + tid;
      int kp2 = idx >> 5, dq = idx & 31;
      vreg[2 * p]     = *reinterpret_cast<const float4*>(vp + (2 * kp2) * Dn + dq * 4);
      vreg[2 * p + 1] = *reinterpret_cast<const float4*>(vp + (2 * kp2 + 1) * Dn + dq * 4);
    }
  };
  auto write_tiles = [&]() {
#pragma unroll
    for (int p = 0; p < 8; p++) {
      int idx = p * 256 + tid;
      int row = idx >> 5, dq = idx & 31;
      float4 x = kreg[p];
      short4v sv;
      sv[0] = f2bf(x.x); sv[1] = f2bf(x.y); sv[2] = f2bf(x.z); sv[3] = f2bf(x.w);
      *reinterpret_cast<short4v*>(&Kt[row * 128 + ((dq * 4) ^ ((row & 7) << 3))]) = sv;
    }
#pragma unroll
    for (int p = 0; p < 4; p++) {
      int idx = p * 256 + tid;
      int kp2 = idx >> 5, dq = idx & 31;
      int swz = (dq & 7) << 3;
      float4 v0 = vreg[2 * p], v1 = vreg[2 * p + 1];
      const float* f0 = &v0.x;
      const float* f1 = &v1.x;
#pragma unroll
      for (int i = 0; i < 4; i++) {
        int d = dq * 4 + i;
        uint32_t pk = ((uint32_t)(uint16_t)f2bf(f0[i])) |
                      (((uint32_t)(uint16_t)f2bf(f1[i])) << 16);
        *reinterpret_cast<uint32_t*>(&Vt[d * 64 + ((2 * kp2) ^ swz)]) = pk;
      }
    }
  };
  auto load_mask = [&](int kt, uint2* dst) {
#pragma unroll
    for (int r = 0; r < 4; r++) {
      uint32_t widx = (uint32_t)(b * SQn + q0 + w * 16 + 4 * h + r) * 64u + (uint32_t)kt;
      dst[r] = maskw2[widx];
    }
  };

  // prologue: prefetch tile 0 into registers
  issue_loads(0);
  uint2 mw_nxt[4];
  if (USE_MASK) load_mask(0, mw_nxt);

  for (int kt = 0; kt < SKn / KTn; kt++) {
    __syncthreads();           // BARRIER-A: all waves done reading tile kt-1
    write_tiles();             // LDS <- regs of tile kt (vmcnt by compiler)
    if (kt + 1 < SKn / KTn) issue_loads(kt + 1);  // in flight across compute
    uint2 mw[4];
    if (USE_MASK) {
#pragma unroll
      for (int r = 0; r < 4; r++) mw[r] = mw_nxt[r];
      if (kt + 1 < SKn / KTn) load_mask(kt + 1, mw_nxt);
    }
    __syncthreads();           // BARRIER-B: tile kt visible

    // ---- QK^T: S[4h+r][t*16+m] (qf pre-scaled) ----
    f32x4 sfr[4];
#pragma unroll
    for (int t = 0; t < 4; t++) {
      f32x4 s = (f32x4){0.f, 0.f, 0.f, 0.f};
      int krow = t * 16 + m;
      int swzk = (krow & 7) << 3;
#pragma unroll
      for (int c = 0; c < 4; c++) {
        short8 kf = *reinterpret_cast<const short8*>(
            &Kt[krow * 128 + ((c * 32 + h * 8) ^ swzk)]);
        s = __builtin_amdgcn_mfma_f32_16x16x32_bf16(qf[c], kf, s, 0, 0, 0);
      }
      sfr[t] = s;
    }

    // ---- online softmax: DPP 16-lane all-reduce (VALU pipe) ----
    float oscl[4];
    float pv[4][4];
#pragma unroll
    for (int r = 0; r < 4; r++) {
      float s0 = sfr[0][r], s1 = sfr[1][r], s2 = sfr[2][r], s3 = sfr[3][r];
      float tmax = redmax16(fmaxf(fmaxf(s0, s1), fmaxf(s2, s3)));
      float mnew = fmaxf(m_run[r], tmax);
      float al = __expf(m_run[r] - mnew);
      float e0 = __expf(s0 - mnew), e1 = __expf(s1 - mnew);
      float e2 = __expf(s2 - mnew), e3 = __expf(s3 - mnew);
      float ts = redsum16(e0 + e1 + e2 + e3);
      l_run[r] = l_run[r] * al + ts;
      m_run[r] = mnew;
      oscl[r] = al;
      pv[0][r] = e0; pv[1][r] = e1; pv[2][r] = e2; pv[3][r] = e3;
    }
#pragma unroll
    for (int dt = 0; dt < 8; dt++) {
#pragma unroll
      for (int r = 0; r < 4; r++) acc[dt][r] *= oscl[r];
    }

    // ---- dropout + write P (wave-private rows) ----
#pragma unroll
    for (int r = 0; r < 4; r++) {
      int qrow = w * 16 + 4 * h + r;
      int psw = (qrow & 8) << 1;
#pragma unroll
      for (int t = 0; t < 4; t++) {
        bool kp;
        if (USE_MASK) {
          uint32_t wm = (t < 2) ? mw[r].x : mw[r].y;
          kp = (wm >> ((t & 1) * 16 + m)) & 1u;
        } else {
          uint32_t n = rowb[r] + (uint32_t)(kt * 64 + t * 16 + m);
          uint32_t o0, o1;
          tf2x32(0u, n, o0, o1);
          kp = keep_from_bits(o0 ^ o1, pkeep);
        }
        float pmv = kp ? pv[t][r] : 0.0f;
        Pt[qrow * 72 + ((t * 16 + m) ^ psw)] = f2bf(pmv);
      }
    }

    // ---- PV: acc += P @ V (Pt rows wave-private; same-wave DS ordering) ----
    {
      int qr = w * 16 + m;
      int psw = (qr & 8) << 1;
#pragma unroll
      for (int c = 0; c < 2; c++) {
        short8 pa = *reinterpret_cast<const short8*>(&Pt[qr * 72 + ((c * 32 + h * 8) ^ psw)]);
#pragma unroll
        for (int dt = 0; dt < 8; dt++) {
          int d = dt * 16 + m;
          short8 vb = *reinterpret_cast<const short8*>(
              &Vt[d * 64 + ((c * 32 + h * 8) ^ (((d >> 2) & 7) << 3))]);
          acc[dt] = __builtin_amdgcn_mfma_f32_16x16x32_bf16(pa, vb, acc[dt], 0, 0, 0);
        }
      }
    }
  }

  // ---- epilogue ----
#pragma unroll
  for (int r = 0; r < 4; r++) {
    float os = oscale_c / l_run[r];
    float* op = Out + (size_t)(b * SQn + q0 + w * 16 + 4 * h + r) * Dn;
#pragma unroll
    for (int dt = 0; dt < 8; dt++) op[dt * 16 + m] = acc[dt][r] * os;
  }
}

extern "C" void kernel_launch(void* const* d_in, const int* in_sizes, int n_in,
                              void* d_out, int out_size, void* d_ws, size_t ws_size,
                              hipStream_t stream) {
  const float* Qg = (const float*)d_in[0];
  const float* Kg = (const float*)d_in[1];
  const float* Vg = (const float*)d_in[2];
  const float* p_inv = (const float*)d_in[3];
  const float* p_pd = (const float*)d_in[4];
  const float* p_pm = (const float*)d_in[5];
  float* Out = (float*)d_out;

  const bool use_mask = ws_size >= (size_t)(NTOT / 8u);
  if (use_mask) {
    mask_gen<<<dim3(NTOT / 32u / 256u), dim3(256), 0, stream>>>(p_pd, (uint32_t*)d_ws);
    attn<1><<<dim3(512), dim3(256), 0, stream>>>(Qg, Kg, Vg, p_inv, p_pd, p_pm,
                                                 (const uint2*)d_ws, Out);
  } else {
    attn<0><<<dim3(512), dim3(256), 0, stream>>>(Qg, Kg, Vg, p_inv, p_pd, p_pm,
                                                 nullptr, Out);
  }
}

// Round 7
// 496.258 us; speedup vs baseline: 1.5058x; 1.1252x over previous
//
#include <hip/hip_runtime.h>
#include <stdint.h>

// Problem: B=8, SQ=SK=4096, D=128, fp32 in/out.
// out = softmax(QK^T/inv_scale) * jax-threefry-dropout-mask / (1-pm) @ V
// RNG fused into attn: bits[n] = o0^o1, (o0,o1)=threefry2x32(key=(0,42),(0,n))
// keep <=> (bits>>9) < ceil((1-pd)*2^23)  [exact == jax uniform<p, see notes]
#define Bn  8
#define SQn 4096
#define SKn 4096
#define Dn  128
#define QTn 64
#define KTn 64

typedef __attribute__((ext_vector_type(8))) short short8;
typedef __attribute__((ext_vector_type(4))) short short4v;
typedef __attribute__((ext_vector_type(4))) float f32x4;

__device__ __forceinline__ short f2bf(float f) {
  uint32_t x = __float_as_uint(f);
  uint32_t r = (x + 0x7FFFu + ((x >> 16) & 1u)) >> 16;
  return (short)r;
}

// 1-instruction rotate: v_alignbit_b32(x,x,32-r) == rotl(x,r)
__device__ __forceinline__ uint32_t rotl32(uint32_t x, int r) {
  return __builtin_amdgcn_alignbit(x, x, (32 - r) & 31);
}

// JAX threefry2x32, key = (0, 42); returns o0^o1 (partitionable fold)
__device__ __forceinline__ uint32_t tf2x32_xor(uint32_t x0, uint32_t x1) {
  const uint32_t k0 = 0u, k1 = 42u, k2 = 0x1BD11BF0u;
  x0 += k0; x1 += k1;
#define TFR(r) { x0 += x1; x1 = rotl32(x1, r); x1 ^= x0; }
  TFR(13) TFR(15) TFR(26) TFR(6)  x0 += k1; x1 += k2 + 1u;
  TFR(17) TFR(29) TFR(16) TFR(24) x0 += k2; x1 += k0 + 2u;
  TFR(13) TFR(15) TFR(26) TFR(6)  x0 += k0; x1 += k1 + 3u;
  TFR(17) TFR(29) TFR(16) TFR(24) x0 += k1; x1 += k2 + 4u;
  TFR(13) TFR(15) TFR(26) TFR(6)  x0 += k2; x1 += k0 + 5u;
#undef TFR
  return x0 ^ x1;
}

// 16-lane (DPP row) rotation all-reduce: VALU-pipe, no LDS traffic.
template <int N>
__device__ __forceinline__ float ror16(float x) {
  int xi = __float_as_int(x);
  int r = __builtin_amdgcn_update_dpp(xi, xi, 0x120 | N, 0xF, 0xF, false);
  return __int_as_float(r);
}
__device__ __forceinline__ float redmax16(float x) {
  x = fmaxf(x, ror16<8>(x)); x = fmaxf(x, ror16<4>(x));
  x = fmaxf(x, ror16<2>(x)); x = fmaxf(x, ror16<1>(x));
  return x;
}
__device__ __forceinline__ float redsum16(float x) {
  x += ror16<8>(x); x += ror16<4>(x); x += ror16<2>(x); x += ror16<1>(x);
  return x;
}

// Flash attention with fused dropout RNG. 256 threads = 4 waves; wave w owns
// q-band [w*16, w*16+16). Two barriers/tile (replay-verified discipline) +
// register prefetch of tile kt+1 issued before barrier-B.
__global__ __launch_bounds__(256, 2) void attn(
    const float* __restrict__ Qg, const float* __restrict__ Kg, const float* __restrict__ Vg,
    const float* __restrict__ p_inv, const float* __restrict__ p_pd, const float* __restrict__ p_pm,
    float* __restrict__ Out) {
  // K tile [key][d] bf16, XOR-swizzle (row&7)<<3 shorts -> 2-way reads
  __shared__ __align__(16) short Kt[KTn * Dn];
  // V tile transposed [d][key] bf16, XOR ((d>>2)&7)<<3 -> ~4-way
  __shared__ __align__(16) short Vt[Dn * KTn];
  // P tile [q][key] bf16, 72-short rows, inner ^ ((q&8)<<1) (wave-private rows)
  __shared__ __align__(16) short Pt[QTn * 72];

  const int tid = threadIdx.x;
  const int w = tid >> 6;
  const int lane = tid & 63;
  const int m = lane & 15;
  const int h = lane >> 4;
  const int gid = blockIdx.x;
  const int b = gid & 7;
  const int q0 = (gid >> 3) * QTn;

  const float rscale = 1.0f / p_inv[0];
  const float pd = p_pd[0], pm = p_pm[0];
  // integer keep-threshold: m23 < ceil(pkeep*2^23)  (exact, see header note)
  const uint32_t ithr = (uint32_t)ceilf((1.0f - pd) * 8388608.0f);
  const float oscale_c = 1.0f / ((1.0f - pd) * (1.0f - pm));

  // ---- preload Q fragments with rscale folded in ----
  short8 qf[4];
  {
    const float* qp = Qg + ((size_t)(b * SQn + q0 + w * 16 + m)) * Dn;
#pragma unroll
    for (int c = 0; c < 4; c++) {
      float4 a = *reinterpret_cast<const float4*>(qp + c * 32 + h * 8);
      float4 a2 = *reinterpret_cast<const float4*>(qp + c * 32 + h * 8 + 4);
      short8 v;
      v[0] = f2bf(a.x * rscale);  v[1] = f2bf(a.y * rscale);
      v[2] = f2bf(a.z * rscale);  v[3] = f2bf(a.w * rscale);
      v[4] = f2bf(a2.x * rscale); v[5] = f2bf(a2.y * rscale);
      v[6] = f2bf(a2.z * rscale); v[7] = f2bf(a2.w * rscale);
      qf[c] = v;
    }
  }

  f32x4 acc[8];
#pragma unroll
  for (int dt = 0; dt < 8; dt++) acc[dt] = (f32x4){0.f, 0.f, 0.f, 0.f};
  float m_run[4], l_run[4];
  uint32_t rowb[4];
#pragma unroll
  for (int r = 0; r < 4; r++) {
    m_run[r] = -1e30f;
    l_run[r] = 0.f;
    rowb[r] = (uint32_t)(b * SQn + q0 + w * 16 + 4 * h + r) * (uint32_t)SKn;
  }

  const size_t kvbase = (size_t)b * SKn * Dn;

  float4 kreg[8], vreg[8];
  auto issue_loads = [&](int kt) {
    const float* kp = Kg + kvbase + (size_t)kt * KTn * Dn;
    const float* vp = Vg + kvbase + (size_t)kt * KTn * Dn;
#pragma unroll
    for (int p = 0; p < 8; p++) {
      int idx = p * 256 + tid;
      kreg[p] = *reinterpret_cast<const float4*>(kp + (idx >> 5) * Dn + (idx & 31) * 4);
    }
#pragma unroll
    for (int p = 0; p < 4; p++) {
      int idx = p * 256 + tid;
      int kp2 = idx >> 5, dq = idx & 31;
      vreg[2 * p]     = *reinterpret_cast<const float4*>(vp + (2 * kp2) * Dn + dq * 4);
      vreg[2 * p + 1] = *reinterpret_cast<const float4*>(vp + (2 * kp2 + 1) * Dn + dq * 4);
    }
  };
  auto write_tiles = [&]() {
#pragma unroll
    for (int p = 0; p < 8; p++) {
      int idx = p * 256 + tid;
      int row = idx >> 5, dq = idx & 31;
      float4 x = kreg[p];
      short4v sv;
      sv[0] = f2bf(x.x); sv[1] = f2bf(x.y); sv[2] = f2bf(x.z); sv[3] = f2bf(x.w);
      *reinterpret_cast<short4v*>(&Kt[row * 128 + ((dq * 4) ^ ((row & 7) << 3))]) = sv;
    }
#pragma unroll
    for (int p = 0; p < 4; p++) {
      int idx = p * 256 + tid;
      int kp2 = idx >> 5, dq = idx & 31;
      int swz = (dq & 7) << 3;
      float4 v0 = vreg[2 * p], v1 = vreg[2 * p + 1];
      const float* f0 = &v0.x;
      const float* f1 = &v1.x;
#pragma unroll
      for (int i = 0; i < 4; i++) {
        int d = dq * 4 + i;
        uint32_t pk = ((uint32_t)(uint16_t)f2bf(f0[i])) |
                      (((uint32_t)(uint16_t)f2bf(f1[i])) << 16);
        *reinterpret_cast<uint32_t*>(&Vt[d * 64 + ((2 * kp2) ^ swz)]) = pk;
      }
    }
  };

  // prologue: prefetch tile 0 into registers
  issue_loads(0);

  for (int kt = 0; kt < SKn / KTn; kt++) {
    __syncthreads();           // BARRIER-A: all waves done reading tile kt-1
    write_tiles();             // LDS <- regs of tile kt
    if (kt + 1 < SKn / KTn) issue_loads(kt + 1);  // in flight across compute
    __syncthreads();           // BARRIER-B: tile kt visible

    // ---- QK^T: S[4h+r][t*16+m] (qf pre-scaled) ----
    f32x4 sfr[4];
#pragma unroll
    for (int t = 0; t < 4; t++) {
      f32x4 s = (f32x4){0.f, 0.f, 0.f, 0.f};
      int krow = t * 16 + m;
      int swzk = (krow & 7) << 3;
#pragma unroll
      for (int c = 0; c < 4; c++) {
        short8 kf = *reinterpret_cast<const short8*>(
            &Kt[krow * 128 + ((c * 32 + h * 8) ^ swzk)]);
        s = __builtin_amdgcn_mfma_f32_16x16x32_bf16(qf[c], kf, s, 0, 0, 0);
      }
      sfr[t] = s;
    }

    // ---- online softmax: DPP 16-lane all-reduce (VALU pipe) ----
    float oscl[4];
    float pv[4][4];
#pragma unroll
    for (int r = 0; r < 4; r++) {
      float s0 = sfr[0][r], s1 = sfr[1][r], s2 = sfr[2][r], s3 = sfr[3][r];
      float tmax = redmax16(fmaxf(fmaxf(s0, s1), fmaxf(s2, s3)));
      float mnew = fmaxf(m_run[r], tmax);
      float al = __expf(m_run[r] - mnew);
      float e0 = __expf(s0 - mnew), e1 = __expf(s1 - mnew);
      float e2 = __expf(s2 - mnew), e3 = __expf(s3 - mnew);
      float ts = redsum16(e0 + e1 + e2 + e3);
      l_run[r] = l_run[r] * al + ts;
      m_run[r] = mnew;
      oscl[r] = al;
      pv[0][r] = e0; pv[1][r] = e1; pv[2][r] = e2; pv[3][r] = e3;
    }
#pragma unroll
    for (int dt = 0; dt < 8; dt++) {
#pragma unroll
      for (int r = 0; r < 4; r++) acc[dt][r] *= oscl[r];
    }

    // ---- fused dropout RNG + write P (16 independent threefry chains) ----
    const uint32_t kbase = (uint32_t)(kt * 64 + m);
#pragma unroll
    for (int r = 0; r < 4; r++) {
      int qrow = w * 16 + 4 * h + r;
      int psw = (qrow & 8) << 1;
      uint32_t nb = rowb[r] + kbase;
#pragma unroll
      for (int t = 0; t < 4; t++) {
        uint32_t bits = tf2x32_xor(0u, nb + (uint32_t)(t * 16));
        bool kp = (bits >> 9) < ithr;
        float pmv = kp ? pv[t][r] : 0.0f;
        Pt[qrow * 72 + ((t * 16 + m) ^ psw)] = f2bf(pmv);
      }
    }

    // ---- PV: acc += P @ V (Pt rows wave-private; same-wave DS ordering) ----
    {
      int qr = w * 16 + m;
      int psw = (qr & 8) << 1;
#pragma unroll
      for (int c = 0; c < 2; c++) {
        short8 pa = *reinterpret_cast<const short8*>(&Pt[qr * 72 + ((c * 32 + h * 8) ^ psw)]);
#pragma unroll
        for (int dt = 0; dt < 8; dt++) {
          int d = dt * 16 + m;
          short8 vb = *reinterpret_cast<const short8*>(
              &Vt[d * 64 + ((c * 32 + h * 8) ^ (((d >> 2) & 7) << 3))]);
          acc[dt] = __builtin_amdgcn_mfma_f32_16x16x32_bf16(pa, vb, acc[dt], 0, 0, 0);
        }
      }
    }
  }

  // ---- epilogue ----
#pragma unroll
  for (int r = 0; r < 4; r++) {
    float os = oscale_c / l_run[r];
    float* op = Out + (size_t)(b * SQn + q0 + w * 16 + 4 * h + r) * Dn;
#pragma unroll
    for (int dt = 0; dt < 8; dt++) op[dt * 16 + m] = acc[dt][r] * os;
  }
}

extern "C" void kernel_launch(void* const* d_in, const int* in_sizes, int n_in,
                              void* d_out, int out_size, void* d_ws, size_t ws_size,
                              hipStream_t stream) {
  const float* Qg = (const float*)d_in[0];
  const float* Kg = (const float*)d_in[1];
  const float* Vg = (const float*)d_in[2];
  const float* p_inv = (const float*)d_in[3];
  const float* p_pd = (const float*)d_in[4];
  const float* p_pm = (const float*)d_in[5];
  float* Out = (float*)d_out;

  attn<<<dim3(512), dim3(256), 0, stream>>>(Qg, Kg, Vg, p_inv, p_pd, p_pm, Out);
}

// Round 8
// 465.752 us; speedup vs baseline: 1.6045x; 1.0655x over previous
//
#include <hip/hip_runtime.h>
#include <stdint.h>

// Problem: B=8, SQ=SK=4096, D=128, fp32 in/out.
// out = softmax(QK^T/inv_scale) * jax-threefry-dropout-mask / (1-pm) @ V
// RNG fused: bits[n] = o0^o1, (o0,o1)=threefry2x32(key=(0,42),(0,n));
// keep <=> (bits>>9) < ceil((1-pd)*2^23)  [exact]
#define Bn  8
#define SQn 4096
#define SKn 4096
#define Dn  128
#define QTn 64
#define KTn 64
static constexpr size_t KV_BYTES = 8ull * 4096 * 128 * 2;  // 8.39 MB per tensor

typedef __attribute__((ext_vector_type(8))) short short8;
typedef __attribute__((ext_vector_type(4))) short short4v;
typedef __attribute__((ext_vector_type(4))) float f32x4;

__device__ __forceinline__ short f2bf(float f) {
  uint32_t x = __float_as_uint(f);
  uint32_t r = (x + 0x7FFFu + ((x >> 16) & 1u)) >> 16;
  return (short)r;
}

// 1-instruction rotate: v_alignbit_b32(x,x,32-r) == rotl(x,r)
__device__ __forceinline__ uint32_t rotl32(uint32_t x, int r) {
  return __builtin_amdgcn_alignbit(x, x, (32 - r) & 31);
}

// JAX threefry2x32, key = (0, 42); returns o0^o1 (partitionable fold)
__device__ __forceinline__ uint32_t tf2x32_xor(uint32_t x0, uint32_t x1) {
  const uint32_t k0 = 0u, k1 = 42u, k2 = 0x1BD11BF0u;
  x0 += k0; x1 += k1;
#define TFR(r) { x0 += x1; x1 = rotl32(x1, r); x1 ^= x0; }
  TFR(13) TFR(15) TFR(26) TFR(6)  x0 += k1; x1 += k2 + 1u;
  TFR(17) TFR(29) TFR(16) TFR(24) x0 += k2; x1 += k0 + 2u;
  TFR(13) TFR(15) TFR(26) TFR(6)  x0 += k0; x1 += k1 + 3u;
  TFR(17) TFR(29) TFR(16) TFR(24) x0 += k1; x1 += k2 + 4u;
  TFR(13) TFR(15) TFR(26) TFR(6)  x0 += k2; x1 += k0 + 5u;
#undef TFR
  return x0 ^ x1;
}

// 16-lane (DPP row) rotation all-reduce: VALU-pipe, no LDS traffic.
template <int N>
__device__ __forceinline__ float ror16(float x) {
  int xi = __float_as_int(x);
  int r = __builtin_amdgcn_update_dpp(xi, xi, 0x120 | N, 0xF, 0xF, false);
  return __int_as_float(r);
}
__device__ __forceinline__ float redmax16(float x) {
  x = fmaxf(x, ror16<8>(x)); x = fmaxf(x, ror16<4>(x));
  x = fmaxf(x, ror16<2>(x)); x = fmaxf(x, ror16<1>(x));
  return x;
}
__device__ __forceinline__ float redsum16(float x) {
  x += ror16<8>(x); x += ror16<4>(x); x += ror16<2>(x); x += ror16<1>(x);
  return x;
}

// async global->LDS, 16B per lane; LDS dest is wave-uniform base (+lane*16 by HW)
__device__ __forceinline__ void gload16(const void* g, void* l) {
  __builtin_amdgcn_global_load_lds(
      (const __attribute__((address_space(1))) uint32_t*)g,
      (__attribute__((address_space(3))) uint32_t*)l, 16, 0, 0);
}

// ---- prep: K -> bf16 pre-swizzled [b][kt][row][col^((row&7)<<3)]
//            V -> bf16 transposed+swizzled [b][kt][d][k^(((d>>2)&7)<<3)]
// so that LINEAR global_load_lds staging lands in the exact swizzled LDS
// layout attn's ds_reads expect (guide rule 21: pre-swizzled source).
__global__ __launch_bounds__(256) void prep(const float* __restrict__ K,
                                            const float* __restrict__ V,
                                            short* __restrict__ Kws,
                                            short* __restrict__ Vws) {
  const int blk = blockIdx.x;       // 0..1023: first 512 = K tiles, rest = V
  const int t = blk & 511;          // b*64 + kt
  const int tid = threadIdx.x;
  if (blk < 512) {
    const float* src = K + (size_t)t * (KTn * Dn);
    short* dst = Kws + (size_t)t * (KTn * Dn);
#pragma unroll
    for (int i = 0; i < 4; i++) {
      int idx = i * 2048 + tid * 8;            // dest element offset (8-aligned)
      int row = idx >> 7, colp = idx & 127;
      int colsrc = colp ^ ((row & 7) << 3);
      float4 a  = *reinterpret_cast<const float4*>(src + row * Dn + colsrc);
      float4 a2 = *reinterpret_cast<const float4*>(src + row * Dn + colsrc + 4);
      short8 v;
      v[0] = f2bf(a.x);  v[1] = f2bf(a.y);  v[2] = f2bf(a.z);  v[3] = f2bf(a.w);
      v[4] = f2bf(a2.x); v[5] = f2bf(a2.y); v[6] = f2bf(a2.z); v[7] = f2bf(a2.w);
      *reinterpret_cast<short8*>(dst + idx) = v;
    }
  } else {
    __shared__ short Vl[KTn][Dn + 2];          // +2 pad: kill transpose conflicts
    const float* src = V + (size_t)t * (KTn * Dn);
#pragma unroll
    for (int i = 0; i < 8; i++) {
      int idx = i * 1024 + tid * 4;            // source element (coalesced)
      int k = idx >> 7, d = idx & 127;
      float4 a = *reinterpret_cast<const float4*>(src + idx);
      Vl[k][d + 0] = f2bf(a.x); Vl[k][d + 1] = f2bf(a.y);
      Vl[k][d + 2] = f2bf(a.z); Vl[k][d + 3] = f2bf(a.w);
    }
    __syncthreads();
    short* dst = Vws + (size_t)t * (KTn * Dn);
#pragma unroll
    for (int i = 0; i < 4; i++) {
      int o = i * 2048 + tid * 8;              // dest element (8-aligned)
      int d = o >> 6, kp = o & 63;
      int ksrc = kp ^ (((d >> 2) & 7) << 3);   // 8-aligned; +j stays contiguous
      short8 v;
#pragma unroll
      for (int j = 0; j < 8; j++) v[j] = Vl[ksrc + j][d];
      *reinterpret_cast<short8*>(dst + o) = v;
    }
  }
}

// ---- main attention: gload_lds staging (zero VALU), LDS double-buffer,
// one barrier per tile (T3 minimum 2-phase; __syncthreads drains vmcnt).
__global__ __launch_bounds__(256, 2) void attn(
    const float* __restrict__ Qg, const short* __restrict__ Kws,
    const short* __restrict__ Vws,
    const float* __restrict__ p_inv, const float* __restrict__ p_pd,
    const float* __restrict__ p_pm, float* __restrict__ Out) {
  __shared__ __align__(16) short Kt[2][KTn * Dn];   // 2 x 16 KB, pre-swizzled
  __shared__ __align__(16) short Vt[2][Dn * KTn];   // 2 x 16 KB, pre-swizzled
  __shared__ __align__(16) short Pt[QTn * 72];      // 9 KB

  const int tid = threadIdx.x;
  const int w = tid >> 6;
  const int lane = tid & 63;
  const int m = lane & 15;
  const int h = lane >> 4;
  const int gid = blockIdx.x;
  const int b = gid & 7;
  const int q0 = (gid >> 3) * QTn;

  const float rscale = 1.0f / p_inv[0];
  const float pd = p_pd[0], pm = p_pm[0];
  const uint32_t ithr = (uint32_t)ceilf((1.0f - pd) * 8388608.0f);
  const float oscale_c = 1.0f / ((1.0f - pd) * (1.0f - pm));

  // ---- preload Q fragments with rscale folded in ----
  short8 qf[4];
  {
    const float* qp = Qg + ((size_t)(b * SQn + q0 + w * 16 + m)) * Dn;
#pragma unroll
    for (int c = 0; c < 4; c++) {
      float4 a = *reinterpret_cast<const float4*>(qp + c * 32 + h * 8);
      float4 a2 = *reinterpret_cast<const float4*>(qp + c * 32 + h * 8 + 4);
      short8 v;
      v[0] = f2bf(a.x * rscale);  v[1] = f2bf(a.y * rscale);
      v[2] = f2bf(a.z * rscale);  v[3] = f2bf(a.w * rscale);
      v[4] = f2bf(a2.x * rscale); v[5] = f2bf(a2.y * rscale);
      v[6] = f2bf(a2.z * rscale); v[7] = f2bf(a2.w * rscale);
      qf[c] = v;
    }
  }

  f32x4 acc[8];
#pragma unroll
  for (int dt = 0; dt < 8; dt++) acc[dt] = (f32x4){0.f, 0.f, 0.f, 0.f};
  float m_run[4], l_run[4];
  uint32_t rowb[4];
#pragma unroll
  for (int r = 0; r < 4; r++) {
    m_run[r] = -1e30f;
    l_run[r] = 0.f;
    rowb[r] = (uint32_t)(b * SQn + q0 + w * 16 + 4 * h + r) * (uint32_t)SKn;
  }

  const char* Kbase = (const char*)(Kws + (size_t)(b * 64) * (KTn * Dn));
  const char* Vbase = (const char*)(Vws + (size_t)(b * 64) * (KTn * Dn));

  // wave w stages bytes [w*4096, (w+1)*4096) of each 16 KB tile
  auto stage = [&](int kt, int buf) {
    const char* ks = Kbase + (size_t)kt * 16384;
    const char* vs = Vbase + (size_t)kt * 16384;
#pragma unroll
    for (int i = 0; i < 4; i++) {
      int off = w * 4096 + i * 1024;     // wave-uniform
      gload16(ks + off + lane * 16, (char*)&Kt[buf][0] + off);
      gload16(vs + off + lane * 16, (char*)&Vt[buf][0] + off);
    }
  };

  stage(0, 0);  // prologue

  for (int kt = 0; kt < SKn / KTn; kt++) {
    const int cur = kt & 1;
    // drains vmcnt(0): tile kt staged; all waves done reading buf[cur^1]
    __syncthreads();
    if (kt + 1 < SKn / KTn) stage(kt + 1, cur ^ 1);  // flies under compute(kt)

    // ---- QK^T: S[4h+r][t*16+m] (qf pre-scaled) ----
    f32x4 sfr[4];
#pragma unroll
    for (int t = 0; t < 4; t++) {
      f32x4 s = (f32x4){0.f, 0.f, 0.f, 0.f};
      int krow = t * 16 + m;
      int swzk = (krow & 7) << 3;
#pragma unroll
      for (int c = 0; c < 4; c++) {
        short8 kf = *reinterpret_cast<const short8*>(
            &Kt[cur][krow * 128 + ((c * 32 + h * 8) ^ swzk)]);
        s = __builtin_amdgcn_mfma_f32_16x16x32_bf16(qf[c], kf, s, 0, 0, 0);
      }
      sfr[t] = s;
    }

    // ---- online softmax: DPP 16-lane all-reduce ----
    float oscl[4];
    float pv[4][4];
#pragma unroll
    for (int r = 0; r < 4; r++) {
      float s0 = sfr[0][r], s1 = sfr[1][r], s2 = sfr[2][r], s3 = sfr[3][r];
      float tmax = redmax16(fmaxf(fmaxf(s0, s1), fmaxf(s2, s3)));
      float mnew = fmaxf(m_run[r], tmax);
      float al = __expf(m_run[r] - mnew);
      float e0 = __expf(s0 - mnew), e1 = __expf(s1 - mnew);
      float e2 = __expf(s2 - mnew), e3 = __expf(s3 - mnew);
      float ts = redsum16(e0 + e1 + e2 + e3);
      l_run[r] = l_run[r] * al + ts;
      m_run[r] = mnew;
      oscl[r] = al;
      pv[0][r] = e0; pv[1][r] = e1; pv[2][r] = e2; pv[3][r] = e3;
    }
#pragma unroll
    for (int dt = 0; dt < 8; dt++) {
#pragma unroll
      for (int r = 0; r < 4; r++) acc[dt][r] *= oscl[r];
    }

    // ---- fused dropout RNG + write P ----
    const uint32_t kbase = (uint32_t)(kt * 64 + m);
#pragma unroll
    for (int r = 0; r < 4; r++) {
      int qrow = w * 16 + 4 * h + r;
      int psw = (qrow & 8) << 1;
      uint32_t nb = rowb[r] + kbase;
#pragma unroll
      for (int t = 0; t < 4; t++) {
        uint32_t bits = tf2x32_xor(0u, nb + (uint32_t)(t * 16));
        bool kp = (bits >> 9) < ithr;
        float pmv = kp ? pv[t][r] : 0.0f;
        Pt[qrow * 72 + ((t * 16 + m) ^ psw)] = f2bf(pmv);
      }
    }

    // ---- PV: acc += P @ V (Pt rows wave-private) ----
    {
      int qr = w * 16 + m;
      int psw = (qr & 8) << 1;
#pragma unroll
      for (int c = 0; c < 2; c++) {
        short8 pa = *reinterpret_cast<const short8*>(&Pt[qr * 72 + ((c * 32 + h * 8) ^ psw)]);
#pragma unroll
        for (int dt = 0; dt < 8; dt++) {
          int d = dt * 16 + m;
          short8 vb = *reinterpret_cast<const short8*>(
              &Vt[cur][d * 64 + ((c * 32 + h * 8) ^ (((d >> 2) & 7) << 3))]);
          acc[dt] = __builtin_amdgcn_mfma_f32_16x16x32_bf16(pa, vb, acc[dt], 0, 0, 0);
        }
      }
    }
  }

  // ---- epilogue ----
#pragma unroll
  for (int r = 0; r < 4; r++) {
    float os = oscale_c / l_run[r];
    float* op = Out + (size_t)(b * SQn + q0 + w * 16 + 4 * h + r) * Dn;
#pragma unroll
    for (int dt = 0; dt < 8; dt++) op[dt * 16 + m] = acc[dt][r] * os;
  }
}

// ---- fallback (round-7 kernel, used only if ws_size too small) ----
__global__ __launch_bounds__(256, 2) void attn_fb(
    const float* __restrict__ Qg, const float* __restrict__ Kg, const float* __restrict__ Vg,
    const float* __restrict__ p_inv, const float* __restrict__ p_pd, const float* __restrict__ p_pm,
    float* __restrict__ Out) {
  __shared__ __align__(16) short Kt[KTn * Dn];
  __shared__ __align__(16) short Vt[Dn * KTn];
  __shared__ __align__(16) short Pt[QTn * 72];
  const int tid = threadIdx.x;
  const int w = tid >> 6;
  const int lane = tid & 63;
  const int m = lane & 15;
  const int h = lane >> 4;
  const int gid = blockIdx.x;
  const int b = gid & 7;
  const int q0 = (gid >> 3) * QTn;
  const float rscale = 1.0f / p_inv[0];
  const float pd = p_pd[0], pm = p_pm[0];
  const uint32_t ithr = (uint32_t)ceilf((1.0f - pd) * 8388608.0f);
  const float oscale_c = 1.0f / ((1.0f - pd) * (1.0f - pm));
  short8 qf[4];
  {
    const float* qp = Qg + ((size_t)(b * SQn + q0 + w * 16 + m)) * Dn;
#pragma unroll
    for (int c = 0; c < 4; c++) {
      float4 a = *reinterpret_cast<const float4*>(qp + c * 32 + h * 8);
      float4 a2 = *reinterpret_cast<const float4*>(qp + c * 32 + h * 8 + 4);
      short8 v;
      v[0] = f2bf(a.x * rscale);  v[1] = f2bf(a.y * rscale);
      v[2] = f2bf(a.z * rscale);  v[3] = f2bf(a.w * rscale);
      v[4] = f2bf(a2.x * rscale); v[5] = f2bf(a2.y * rscale);
      v[6] = f2bf(a2.z * rscale); v[7] = f2bf(a2.w * rscale);
      qf[c] = v;
    }
  }
  f32x4 acc[8];
#pragma unroll
  for (int dt = 0; dt < 8; dt++) acc[dt] = (f32x4){0.f, 0.f, 0.f, 0.f};
  float m_run[4], l_run[4];
  uint32_t rowb[4];
#pragma unroll
  for (int r = 0; r < 4; r++) {
    m_run[r] = -1e30f; l_run[r] = 0.f;
    rowb[r] = (uint32_t)(b * SQn + q0 + w * 16 + 4 * h + r) * (uint32_t)SKn;
  }
  const size_t kvbase = (size_t)b * SKn * Dn;
  float4 kreg[8], vreg[8];
  auto issue_loads = [&](int kt) {
    const float* kp = Kg + kvbase + (size_t)kt * KTn * Dn;
    const float* vp = Vg + kvbase + (size_t)kt * KTn * Dn;
#pragma unroll
    for (int p = 0; p < 8; p++) {
      int idx = p * 256 + tid;
      kreg[p] = *reinterpret_cast<const float4*>(kp + (idx >> 5) * Dn + (idx & 31) * 4);
    }
#pragma unroll
    for (int p = 0; p < 4; p++) {
      int idx = p * 256 + tid;
      int kp2 = idx >> 5, dq = idx & 31;
      vreg[2 * p]     = *reinterpret_cast<const float4*>(vp + (2 * kp2) * Dn + dq * 4);
      vreg[2 * p + 1] = *reinterpret_cast<const float4*>(vp + (2 * kp2 + 1) * Dn + dq * 4);
    }
  };
  auto write_tiles = [&]() {
#pragma unroll
    for (int p = 0; p < 8; p++) {
      int idx = p * 256 + tid;
      int row = idx >> 5, dq = idx & 31;
      float4 x = kreg[p];
      short4v sv;
      sv[0] = f2bf(x.x); sv[1] = f2bf(x.y); sv[2] = f2bf(x.z); sv[3] = f2bf(x.w);
      *reinterpret_cast<short4v*>(&Kt[row * 128 + ((dq * 4) ^ ((row & 7) << 3))]) = sv;
    }
#pragma unroll
    for (int p = 0; p < 4; p++) {
      int idx = p * 256 + tid;
      int kp2 = idx >> 5, dq = idx & 31;
      int swz = (dq & 7) << 3;
      float4 v0 = vreg[2 * p], v1 = vreg[2 * p + 1];
      const float* f0 = &v0.x;
      const float* f1 = &v1.x;
#pragma unroll
      for (int i = 0; i < 4; i++) {
        int d = dq * 4 + i;
        uint32_t pk = ((uint32_t)(uint16_t)f2bf(f0[i])) |
                      (((uint32_t)(uint16_t)f2bf(f1[i])) << 16);
        *reinterpret_cast<uint32_t*>(&Vt[d * 64 + ((2 * kp2) ^ swz)]) = pk;
      }
    }
  };
  issue_loads(0);
  for (int kt = 0; kt < SKn / KTn; kt++) {
    __syncthreads();
    write_tiles();
    if (kt + 1 < SKn / KTn) issue_loads(kt + 1);
    __syncthreads();
    f32x4 sfr[4];
#pragma unroll
    for (int t = 0; t < 4; t++) {
      f32x4 s = (f32x4){0.f, 0.f, 0.f, 0.f};
      int krow = t * 16 + m;
      int swzk = (krow & 7) << 3;
#pragma unroll
      for (int c = 0; c < 4; c++) {
        short8 kf = *reinterpret_cast<const short8*>(
            &Kt[krow * 128 + ((c * 32 + h * 8) ^ swzk)]);
        s = __builtin_amdgcn_mfma_f32_16x16x32_bf16(qf[c], kf, s, 0, 0, 0);
      }
      sfr[t] = s;
    }
    float oscl[4];
    float pv[4][4];
#pragma unroll
    for (int r = 0; r < 4; r++) {
      float s0 = sfr[0][r], s1 = sfr[1][r], s2 = sfr[2][r], s3 = sfr[3][r];
      float tmax = redmax16(fmaxf(fmaxf(s0, s1), fmaxf(s2, s3)));
      float mnew = fmaxf(m_run[r], tmax);
      float al = __expf(m_run[r] - mnew);
      float e0 = __expf(s0 - mnew), e1 = __expf(s1 - mnew);
      float e2 = __expf(s2 - mnew), e3 = __expf(s3 - mnew);
      float ts = redsum16(e0 + e1 + e2 + e3);
      l_run[r] = l_run[r] * al + ts;
      m_run[r] = mnew;
      oscl[r] = al;
      pv[0][r] = e0; pv[1][r] = e1; pv[2][r] = e2; pv[3][r] = e3;
    }
#pragma unroll
    for (int dt = 0; dt < 8; dt++) {
#pragma unroll
      for (int r = 0; r < 4; r++) acc[dt][r] *= oscl[r];
    }
    const uint32_t kbase = (uint32_t)(kt * 64 + m);
#pragma unroll
    for (int r = 0; r < 4; r++) {
      int qrow = w * 16 + 4 * h + r;
      int psw = (qrow & 8) << 1;
      uint32_t nb = rowb[r] + kbase;
#pragma unroll
      for (int t = 0; t < 4; t++) {
        uint32_t bits = tf2x32_xor(0u, nb + (uint32_t)(t * 16));
        bool kp = (bits >> 9) < ithr;
        float pmv = kp ? pv[t][r] : 0.0f;
        Pt[qrow * 72 + ((t * 16 + m) ^ psw)] = f2bf(pmv);
      }
    }
    {
      int qr = w * 16 + m;
      int psw = (qr & 8) << 1;
#pragma unroll
      for (int c = 0; c < 2; c++) {
        short8 pa = *reinterpret_cast<const short8*>(&Pt[qr * 72 + ((c * 32 + h * 8) ^ psw)]);
#pragma unroll
        for (int dt = 0; dt < 8; dt++) {
          int d = dt * 16 + m;
          short8 vb = *reinterpret_cast<const short8*>(
              &Vt[d * 64 + ((c * 32 + h * 8) ^ (((d >> 2) & 7) << 3))]);
          acc[dt] = __builtin_amdgcn_mfma_f32_16x16x32_bf16(pa, vb, acc[dt], 0, 0, 0);
        }
      }
    }
  }
#pragma unroll
  for (int r = 0; r < 4; r++) {
    float os = oscale_c / l_run[r];
    float* op = Out + (size_t)(b * SQn + q0 + w * 16 + 4 * h + r) * Dn;
#pragma unroll
    for (int dt = 0; dt < 8; dt++) op[dt * 16 + m] = acc[dt][r] * os;
  }
}

extern "C" void kernel_launch(void* const* d_in, const int* in_sizes, int n_in,
                              void* d_out, int out_size, void* d_ws, size_t ws_size,
                              hipStream_t stream) {
  const float* Qg = (const float*)d_in[0];
  const float* Kg = (const float*)d_in[1];
  const float* Vg = (const float*)d_in[2];
  const float* p_inv = (const float*)d_in[3];
  const float* p_pd = (const float*)d_in[4];
  const float* p_pm = (const float*)d_in[5];
  float* Out = (float*)d_out;

  if (ws_size >= 2 * KV_BYTES) {
    short* Kws = (short*)d_ws;
    short* Vws = (short*)((char*)d_ws + KV_BYTES);
    prep<<<dim3(1024), dim3(256), 0, stream>>>(Kg, Vg, Kws, Vws);
    attn<<<dim3(512), dim3(256), 0, stream>>>(Qg, Kws, Vws, p_inv, p_pd, p_pm, Out);
  } else {
    attn_fb<<<dim3(512), dim3(256), 0, stream>>>(Qg, Kg, Vg, p_inv, p_pd, p_pm, Out);
  }
}